// Round 1
// baseline (37.654 us; speedup 1.0000x reference)
//
#include <hip/hip_runtime.h>
#include <math.h>

#define Hd 512
#define Bn 8
#define Sn 8192

// ---------------------------------------------------------------------------
// K1: v[b,h] = sum_k hidden[b,k] * W[k,h]   (partial-k per block, atomicAdd)
// grid (Bn, 16 k-chunks of 32), block 256
// ---------------------------------------------------------------------------
__global__ __launch_bounds__(256) void k_proj(const float* __restrict__ hidden,
                                              const float* __restrict__ W,
                                              float* __restrict__ v) {
    const int b  = blockIdx.x;
    const int kc = blockIdx.y;
    const int t  = threadIdx.x;
    __shared__ float hs[32];
    if (t < 32) hs[t] = hidden[b * Hd + kc * 32 + t];
    __syncthreads();
    float acc0 = 0.f, acc1 = 0.f;
    const float* Wp = W + (size_t)(kc * 32) * Hd;
    #pragma unroll
    for (int k = 0; k < 32; ++k) {
        const float hk = hs[k];
        acc0 += hk * Wp[(size_t)k * Hd + t];
        acc1 += hk * Wp[(size_t)k * Hd + t + 256];
    }
    atomicAdd(&v[b * Hd + t],       acc0);
    atomicAdd(&v[b * Hd + t + 256], acc1);
}

// ---------------------------------------------------------------------------
// K2: e[b,s] = enc[b,s,:] . v[b,:]
// grid (Sn/64, Bn), block 256 (4 waves); each wave computes 16 rows.
// Lanes split H=512 into 2 x float4; v slice kept in registers.
// ---------------------------------------------------------------------------
__global__ __launch_bounds__(256) void k_energy(const float* __restrict__ enc,
                                                const float* __restrict__ v,
                                                float* __restrict__ e) {
    const int b    = blockIdx.y;
    const int wave = threadIdx.x >> 6;
    const int lane = threadIdx.x & 63;

    const float4* vp = (const float4*)(v + b * Hd);
    const float4 v0 = vp[lane];
    const float4 v1 = vp[64 + lane];

    const int row0 = blockIdx.x * 64 + wave * 16;
    const float4* base = (const float4*)(enc + ((size_t)b * Sn + row0) * Hd);

    #pragma unroll 4
    for (int r = 0; r < 16; ++r) {
        const float4* rowp = base + (size_t)r * (Hd / 4);
        const float4 a0 = rowp[lane];
        const float4 a1 = rowp[64 + lane];
        float p = a0.x * v0.x + a0.y * v0.y + a0.z * v0.z + a0.w * v0.w
                + a1.x * v1.x + a1.y * v1.y + a1.z * v1.z + a1.w * v1.w;
        #pragma unroll
        for (int off = 32; off >= 1; off >>= 1)
            p += __shfl_xor(p, off, 64);
        if (lane == 0) e[(size_t)b * Sn + row0 + r] = p;
    }
}

// ---------------------------------------------------------------------------
// K3: out[b,:] = softmax(e[b,:])   one block per b, 1024 threads, 8 vals each
// ---------------------------------------------------------------------------
__global__ __launch_bounds__(1024) void k_softmax(const float* __restrict__ e,
                                                  float* __restrict__ out) {
    const int b = blockIdx.x;
    const int t = threadIdx.x;
    const int wave = t >> 6, lane = t & 63;
    const float* eb = e + (size_t)b * Sn;

    float vals[8];
    float m = -INFINITY;
    #pragma unroll
    for (int i = 0; i < 8; ++i) {
        vals[i] = eb[t + i * 1024];
        m = fmaxf(m, vals[i]);
    }
    #pragma unroll
    for (int off = 32; off >= 1; off >>= 1)
        m = fmaxf(m, __shfl_xor(m, off, 64));

    __shared__ float red[16];
    if (lane == 0) red[wave] = m;
    __syncthreads();
    if (t < 16) {
        float mm = red[t];
        #pragma unroll
        for (int off = 8; off >= 1; off >>= 1)
            mm = fmaxf(mm, __shfl_xor(mm, off, 16));
        if (t == 0) red[0] = mm;
    }
    __syncthreads();
    m = red[0];
    __syncthreads();

    float s = 0.f;
    #pragma unroll
    for (int i = 0; i < 8; ++i) {
        vals[i] = __expf(vals[i] - m);
        s += vals[i];
    }
    #pragma unroll
    for (int off = 32; off >= 1; off >>= 1)
        s += __shfl_xor(s, off, 64);
    if (lane == 0) red[wave] = s;
    __syncthreads();
    if (t < 16) {
        float ss = red[t];
        #pragma unroll
        for (int off = 8; off >= 1; off >>= 1)
            ss += __shfl_xor(ss, off, 16);
        if (t == 0) red[0] = ss;
    }
    __syncthreads();
    const float inv = 1.0f / red[0];

    #pragma unroll
    for (int i = 0; i < 8; ++i)
        out[(size_t)b * Sn + t + i * 1024] = vals[i] * inv;
}

// ---------------------------------------------------------------------------
extern "C" void kernel_launch(void* const* d_in, const int* in_sizes, int n_in,
                              void* d_out, int out_size, void* d_ws, size_t ws_size,
                              hipStream_t stream) {
    const float* hidden = (const float*)d_in[0];   // [1,B,H]
    const float* enc    = (const float*)d_in[1];   // [B,S,H]
    const float* W      = (const float*)d_in[2];   // [H,H]
    // d_in[3] (bias) intentionally unused: softmax over s is shift-invariant,
    // and bias contributes only a per-(b) constant c[b] = bias . h[b].
    float* out = (float*)d_out;                    // [B,S] f32

    float* v = (float*)d_ws;                       // Bn*Hd floats
    float* e = v + Bn * Hd;                        // Bn*Sn floats

    hipMemsetAsync(v, 0, Bn * Hd * sizeof(float), stream);
    k_proj   <<<dim3(Bn, 16),     256,  0, stream>>>(hidden, W, v);
    k_energy <<<dim3(Sn / 64, Bn), 256, 0, stream>>>(enc, v, e);
    k_softmax<<<Bn,               1024, 0, stream>>>(e, out);
}

// Round 2
// 35.377 us; speedup vs baseline: 1.0644x; 1.0644x over previous
//
#include <hip/hip_runtime.h>
#include <math.h>

#define Hd 512
#define Bn 8
#define Sn 8192
#define KC 16   // k-chunks in proj

// ---------------------------------------------------------------------------
// K1: vpart[kc][b][h] = sum_{k in chunk kc} hidden[b,k] * W[k,h]
// grid (Bn, KC), block 256. No atomics, no zero-init needed.
// ---------------------------------------------------------------------------
__global__ __launch_bounds__(256) void k_proj(const float* __restrict__ hidden,
                                              const float* __restrict__ W,
                                              float* __restrict__ vpart) {
    const int b  = blockIdx.x;
    const int kc = blockIdx.y;
    const int t  = threadIdx.x;
    __shared__ float hs[32];
    if (t < 32) hs[t] = hidden[b * Hd + kc * 32 + t];
    __syncthreads();
    float acc0 = 0.f, acc1 = 0.f;
    const float* Wp = W + (size_t)(kc * 32) * Hd;
    #pragma unroll
    for (int k = 0; k < 32; ++k) {
        const float hk = hs[k];
        acc0 += hk * Wp[(size_t)k * Hd + t];
        acc1 += hk * Wp[(size_t)k * Hd + t + 256];
    }
    float* vo = vpart + ((size_t)kc * Bn + b) * Hd;
    vo[t]       = acc0;
    vo[t + 256] = acc1;
}

// ---------------------------------------------------------------------------
// K2: e[b,s] = enc[b,s,:] . v[b,:]   with v = sum over the 16 slabs.
// grid (Sn/32, Bn), block 256 (4 waves); each wave computes 8 rows.
// Packed 4-row butterfly reduce: 10 shfl per 4 rows instead of 24.
// ---------------------------------------------------------------------------
__global__ __launch_bounds__(256) void k_energy(const float* __restrict__ enc,
                                                const float* __restrict__ vpart,
                                                float* __restrict__ e) {
    const int b    = blockIdx.y;
    const int wave = threadIdx.x >> 6;
    const int lane = threadIdx.x & 63;

    // Reconstruct this lane's slice of v[b] by summing the 16 k-partials.
    float4 v0 = make_float4(0.f, 0.f, 0.f, 0.f);
    float4 v1 = make_float4(0.f, 0.f, 0.f, 0.f);
    #pragma unroll 4
    for (int kc = 0; kc < KC; ++kc) {
        const float4* sp = (const float4*)(vpart + ((size_t)kc * Bn + b) * Hd);
        const float4 a = sp[lane];
        const float4 c = sp[64 + lane];
        v0.x += a.x; v0.y += a.y; v0.z += a.z; v0.w += a.w;
        v1.x += c.x; v1.y += c.y; v1.z += c.z; v1.w += c.w;
    }

    const int row0 = blockIdx.x * 32 + wave * 8;
    const float4* base = (const float4*)(enc + ((size_t)b * Sn + row0) * Hd);

    #pragma unroll
    for (int rb = 0; rb < 8; rb += 4) {
        float p[4];
        #pragma unroll
        for (int r = 0; r < 4; ++r) {
            const float4* rowp = base + (size_t)(rb + r) * (Hd / 4);
            const float4 a0 = rowp[lane];
            const float4 a1 = rowp[64 + lane];
            p[r] = a0.x * v0.x + a0.y * v0.y + a0.z * v0.z + a0.w * v0.w
                 + a1.x * v1.x + a1.y * v1.y + a1.z * v1.z + a1.w * v1.w;
        }
        // packed reduce: rows rb..rb+3 reduced with shared butterfly steps
        float s0 = p[0] + __shfl_xor(p[0], 1, 64);
        float s1 = p[1] + __shfl_xor(p[1], 1, 64);
        float s2 = p[2] + __shfl_xor(p[2], 1, 64);
        float s3 = p[3] + __shfl_xor(p[3], 1, 64);
        float t0 = (lane & 1) ? s1 : s0;
        float t1 = (lane & 1) ? s3 : s2;
        t0 += __shfl_xor(t0, 2, 64);
        t1 += __shfl_xor(t1, 2, 64);
        float w = (lane & 2) ? t1 : t0;
        w += __shfl_xor(w, 4, 64);
        w += __shfl_xor(w, 8, 64);
        w += __shfl_xor(w, 16, 64);
        w += __shfl_xor(w, 32, 64);
        // lane l (l<4) holds full sum of row rb+l
        if (lane < 4) e[(size_t)b * Sn + row0 + rb + lane] = w;
    }
}

// ---------------------------------------------------------------------------
// K3: out[b,:] = softmax(e[b,:])   one block per b, 1024 threads, 8 vals each
// ---------------------------------------------------------------------------
__global__ __launch_bounds__(1024) void k_softmax(const float* __restrict__ e,
                                                  float* __restrict__ out) {
    const int b = blockIdx.x;
    const int t = threadIdx.x;
    const int wave = t >> 6, lane = t & 63;
    const float* eb = e + (size_t)b * Sn;

    float vals[8];
    float m = -INFINITY;
    #pragma unroll
    for (int i = 0; i < 8; ++i) {
        vals[i] = eb[t + i * 1024];
        m = fmaxf(m, vals[i]);
    }
    #pragma unroll
    for (int off = 32; off >= 1; off >>= 1)
        m = fmaxf(m, __shfl_xor(m, off, 64));

    __shared__ float red[16];
    if (lane == 0) red[wave] = m;
    __syncthreads();
    if (t < 16) {
        float mm = red[t];
        #pragma unroll
        for (int off = 8; off >= 1; off >>= 1)
            mm = fmaxf(mm, __shfl_xor(mm, off, 16));
        if (t == 0) red[0] = mm;
    }
    __syncthreads();
    m = red[0];
    __syncthreads();

    float s = 0.f;
    #pragma unroll
    for (int i = 0; i < 8; ++i) {
        vals[i] = __expf(vals[i] - m);
        s += vals[i];
    }
    #pragma unroll
    for (int off = 32; off >= 1; off >>= 1)
        s += __shfl_xor(s, off, 64);
    if (lane == 0) red[wave] = s;
    __syncthreads();
    if (t < 16) {
        float ss = red[t];
        #pragma unroll
        for (int off = 8; off >= 1; off >>= 1)
            ss += __shfl_xor(ss, off, 16);
        if (t == 0) red[0] = ss;
    }
    __syncthreads();
    const float inv = 1.0f / red[0];

    #pragma unroll
    for (int i = 0; i < 8; ++i)
        out[(size_t)b * Sn + t + i * 1024] = vals[i] * inv;
}

// ---------------------------------------------------------------------------
extern "C" void kernel_launch(void* const* d_in, const int* in_sizes, int n_in,
                              void* d_out, int out_size, void* d_ws, size_t ws_size,
                              hipStream_t stream) {
    const float* hidden = (const float*)d_in[0];   // [1,B,H]
    const float* enc    = (const float*)d_in[1];   // [B,S,H]
    const float* W      = (const float*)d_in[2];   // [H,H]
    // d_in[3] (bias) unused: softmax over s is shift-invariant; bias adds a
    // per-b constant c[b] = bias . h[b] that cancels.
    float* out = (float*)d_out;                    // [B,S] f32

    float* vpart = (float*)d_ws;                   // KC*Bn*Hd floats (256 KB)
    float* e     = vpart + KC * Bn * Hd;           // Bn*Sn floats (256 KB)

    k_proj   <<<dim3(Bn, KC),      256,  0, stream>>>(hidden, W, vpart);
    k_energy <<<dim3(Sn / 32, Bn), 256,  0, stream>>>(enc, vpart, e);
    k_softmax<<<Bn,                1024, 0, stream>>>(e, out);
}